// Round 2
// baseline (1220.637 us; speedup 1.0000x reference)
//
#include <hip/hip_runtime.h>
#include <hip/hip_bf16.h>

__device__ __forceinline__ float silu_f(float x) { return x / (1.f + __expf(-x)); }

// float atomic max via signed/unsigned int ordering trick (NaN-free values)
__device__ __forceinline__ void atomicMaxF(float* addr, float val) {
    if (val >= 0.f) atomicMax((int*)addr, __float_as_int(val));
    else            atomicMin((unsigned int*)addr, __float_as_uint(val));
}

__global__ void fill_kernel(float* __restrict__ p, float v, int n) {
    int i = blockIdx.x * blockDim.x + threadIdx.x;
    if (i < n) p[i] = v;
}

// s[n,h] = silu(x[n,:] @ W[:,h] + b[h]);  block = 96 threads (h), grid = N
__global__ void embed_kernel(const float* __restrict__ x, const float* __restrict__ W,
                             const float* __restrict__ b, float* __restrict__ s, int D) {
    int n = blockIdx.x, h = threadIdx.x;
    const float* xrow = x + (size_t)n * D;
    float acc = b[h];
    for (int d = 0; d < D; ++d) acc += xrow[d] * W[d * 96 + h];
    s[(size_t)n * 96 + h] = silu_f(acc);
}

// one or two HxH linears from f32 node features; block = 96, grid = N
__global__ void lin_kernel(const float* __restrict__ s,
                           const float* __restrict__ W1, const float* __restrict__ b1,
                           const float* __restrict__ W2, const float* __restrict__ b2,
                           float* __restrict__ o1, float* __restrict__ o2) {
    __shared__ float row[96];
    int n = blockIdx.x, h = threadIdx.x;
    row[h] = s[(size_t)n * 96 + h];
    __syncthreads();
    float a1 = b1[h];
    if (W2) {
        float a2 = b2[h];
        for (int k = 0; k < 96; ++k) {
            float sv = row[k];
            a1 += sv * W1[k * 96 + h];
            a2 += sv * W2[k * 96 + h];
        }
        o1[(size_t)n * 96 + h] = a1;
        o2[(size_t)n * 96 + h] = a2;
    } else {
        for (int k = 0; k < 96; ++k) a1 += row[k] * W1[k * 96 + h];
        o1[(size_t)n * 96 + h] = a1;
    }
}

// per-edge GATv2 logit: rbf(dist) @ We fused with leaky_relu(xl[src]+xr[tgt]+ve) . att
__global__ void edge_logit_kernel(const int* __restrict__ src, const int* __restrict__ tgt,
                                  const float* __restrict__ pos,
                                  const float* __restrict__ xl, const float* __restrict__ xr,
                                  const float* __restrict__ We, const float* __restrict__ att,
                                  float* __restrict__ elog, float* __restrict__ m, int E) {
    __shared__ float sWe[16 * 96];
    __shared__ float sAtt[96];
    for (int i = threadIdx.x; i < 16 * 96; i += blockDim.x) sWe[i] = We[i];
    for (int i = threadIdx.x; i < 96; i += blockDim.x) sAtt[i] = att[i];
    __syncthreads();
    int e = blockIdx.x * blockDim.x + threadIdx.x;
    if (e >= E) return;
    int si = src[e], ti = tgt[e];
    float dx = pos[si * 3 + 0] - pos[ti * 3 + 0];
    float dy = pos[si * 3 + 1] - pos[ti * 3 + 1];
    float dz = pos[si * 3 + 2] - pos[ti * 3 + 2];
    float d = sqrtf(dx * dx + dy * dy + dz * dz);
    float rbf[16];
#pragma unroll
    for (int g = 0; g < 16; ++g) {
        float t = d - (10.f / 15.f) * (float)g;
        rbf[g] = __expf(-1.125f * t * t);  // -0.5/(10/15)^2
    }
    const float4* xl4 = (const float4*)(xl + (size_t)si * 96);
    const float4* xr4 = (const float4*)(xr + (size_t)ti * 96);
    float logit = 0.f;
#pragma unroll 6
    for (int hh = 0; hh < 24; ++hh) {
        float4 a = xl4[hh], b = xr4[hh];
        float v0 = a.x + b.x, v1 = a.y + b.y, v2 = a.z + b.z, v3 = a.w + b.w;
        int h = hh * 4;
#pragma unroll
        for (int g = 0; g < 16; ++g) {
            float r = rbf[g];
            const float* wp = &sWe[g * 96 + h];
            v0 += r * wp[0]; v1 += r * wp[1]; v2 += r * wp[2]; v3 += r * wp[3];
        }
        v0 = v0 >= 0.f ? v0 : 0.2f * v0;
        v1 = v1 >= 0.f ? v1 : 0.2f * v1;
        v2 = v2 >= 0.f ? v2 : 0.2f * v2;
        v3 = v3 >= 0.f ? v3 : 0.2f * v3;
        logit += v0 * sAtt[h] + v1 * sAtt[h + 1] + v2 * sAtt[h + 2] + v3 * sAtt[h + 3];
    }
    elog[e] = logit;
    atomicMaxF(&m[ti], logit);
}

__global__ void edge_denom_kernel(const int* __restrict__ tgt, const float* __restrict__ elog,
                                  const float* __restrict__ m, float* __restrict__ denom, int E) {
    int e = blockIdx.x * blockDim.x + threadIdx.x;
    if (e >= E) return;
    int ti = tgt[e];
    atomicAdd(&denom[ti], __expf(elog[e] - m[ti]));
}

// block = 384 (4 edges x 96 h); agg[tgt,h] += alpha * xl[src,h]
__global__ void edge_scatter_kernel(const int* __restrict__ src, const int* __restrict__ tgt,
                                    const float* __restrict__ elog, const float* __restrict__ m,
                                    const float* __restrict__ denom, const float* __restrict__ xl,
                                    float* __restrict__ agg, int E) {
    int t = threadIdx.x;
    int e = blockIdx.x * 4 + t / 96;
    int h = t % 96;
    if (e >= E) return;
    int si = src[e], ti = tgt[e];
    float alpha = __expf(elog[e] - m[ti]) / denom[ti];
    atomicAdd(&agg[(size_t)ti * 96 + h], alpha * xl[(size_t)si * 96 + h]);
}

__global__ void node_update_kernel(float* __restrict__ s, const float* __restrict__ agg,
                                   const float* __restrict__ bias, int total) {
    int i = blockIdx.x * blockDim.x + threadIdx.x;
    if (i >= total) return;
    int h = i % 96;
    s[i] += silu_f(agg[i] + bias[h]);
}

// s_L += silu(s_L @ Win + b_in)[:, :192] @ Wout + bout ; block = 192, grid = N_L
__global__ void ssm_kernel(float* __restrict__ sL, const float* __restrict__ Win,
                           const float* __restrict__ b_in, const float* __restrict__ Wout,
                           const float* __restrict__ bout) {
    __shared__ float row[96];
    __shared__ float u[192];
    int n = blockIdx.x, t = threadIdx.x;
    if (t < 96) row[t] = sL[(size_t)n * 96 + t];
    __syncthreads();
    float acc = b_in[t];
    for (int k = 0; k < 96; ++k) acc += row[k] * Win[k * 384 + t];
    u[t] = silu_f(acc);
    __syncthreads();
    if (t < 96) {
        float d = bout[t];
        for (int j = 0; j < 192; ++j) d += u[j] * Wout[j * 96 + t];
        sL[(size_t)n * 96 + t] = row[t] + d;
    }
}

// per-cross-edge q.k/8 + global max reduce; block = 256
__global__ void cross_logit_kernel(const int* __restrict__ csrc, const int* __restrict__ ctgt,
                                   const float* __restrict__ qn, const float* __restrict__ kn,
                                   float* __restrict__ clog, float* __restrict__ csc, int E) {
    int e = blockIdx.x * blockDim.x + threadIdx.x;
    float logit = -__builtin_inff();
    if (e < E) {
        int si = csrc[e], ti = ctgt[e];
        const float4* q4 = (const float4*)(qn + (size_t)ti * 96);
        const float4* k4 = (const float4*)(kn + (size_t)si * 96);
        float acc = 0.f;
#pragma unroll
        for (int i = 0; i < 24; ++i) {
            float4 a = q4[i], b = k4[i];
            acc += a.x * b.x + a.y * b.y + a.z * b.z + a.w * b.w;
        }
        logit = acc * 0.125f;
        clog[e] = logit;
    }
    __shared__ float red[256];
    red[threadIdx.x] = logit;
    __syncthreads();
    for (int s = 128; s > 0; s >>= 1) {
        if (threadIdx.x < s) red[threadIdx.x] = fmaxf(red[threadIdx.x], red[threadIdx.x + s]);
        __syncthreads();
    }
    if (threadIdx.x == 0) atomicMaxF(&csc[0], red[0]);
}

__global__ void cross_denom_kernel(const float* __restrict__ clog, float* __restrict__ csc, int E) {
    int e = blockIdx.x * blockDim.x + threadIdx.x;
    float a = 0.f;
    float mg = csc[0];
    if (e < E) a = __expf(clog[e] - mg);
    __shared__ float red[256];
    red[threadIdx.x] = a;
    __syncthreads();
    for (int s = 128; s > 0; s >>= 1) {
        if (threadIdx.x < s) red[threadIdx.x] += red[threadIdx.x + s];
        __syncthreads();
    }
    if (threadIdx.x == 0) atomicAdd(&csc[1], red[0]);
}

// block = 384 (4 edges x 96); s_L[tgt,h] += attn * vn[src,h]
__global__ void cross_scatter_kernel(const int* __restrict__ csrc, const int* __restrict__ ctgt,
                                     const float* __restrict__ clog, const float* __restrict__ csc,
                                     const float* __restrict__ vn, float* __restrict__ sL, int E) {
    int t = threadIdx.x;
    int e = blockIdx.x * 4 + t / 96;
    int h = t % 96;
    if (e >= E) return;
    float attn = __expf(clog[e] - csc[0]) / csc[1];
    atomicAdd(&sL[(size_t)ctgt[e] * 96 + h], attn * vn[(size_t)csrc[e] * 96 + h]);
}

// out[n,c] = silu(s_L @ W1 + b1) @ W2 + b2 ; block = 96, grid = N_L
__global__ void head_kernel(const float* __restrict__ sL, const float* __restrict__ W1,
                            const float* __restrict__ b1, const float* __restrict__ W2,
                            const float* __restrict__ b2, float* __restrict__ out) {
    __shared__ float row[96];
    __shared__ float tt[96];
    int n = blockIdx.x, h = threadIdx.x;
    row[h] = sL[(size_t)n * 96 + h];
    __syncthreads();
    float a = b1[h];
    for (int k = 0; k < 96; ++k) a += row[k] * W1[k * 96 + h];
    tt[h] = silu_f(a);
    __syncthreads();
    if (h < 3) {
        float o = b2[h];
        for (int j = 0; j < 96; ++j) o += tt[j] * W2[j * 3 + h];
        out[n * 3 + h] = o;
    }
}

static inline int cdiv(int a, int b) { return (a + b - 1) / b; }

extern "C" void kernel_launch(void* const* d_in, const int* in_sizes, int n_in,
                              void* d_out, int out_size, void* d_ws, size_t ws_size,
                              hipStream_t stream) {
    const float* x_L   = (const float*)d_in[0];
    const float* pos_L = (const float*)d_in[1];
    const float* x_P   = (const float*)d_in[2];
    const float* pos_P = (const float*)d_in[3];
    const int* edge_L = (const int*)d_in[4];
    const int* edge_P = (const int*)d_in[5];
    const int* csrc   = (const int*)d_in[6];
    const int* ctgt   = (const int*)d_in[7];
    const float *Wemb_L = (const float*)d_in[8],  *bemb_L = (const float*)d_in[9];
    const float *Wl_L = (const float*)d_in[10], *bl_L = (const float*)d_in[11];
    const float *Wr_L = (const float*)d_in[12], *br_L = (const float*)d_in[13];
    const float *We_L = (const float*)d_in[14], *att_L = (const float*)d_in[15], *bias_L = (const float*)d_in[16];
    const float *Wemb_P = (const float*)d_in[17], *bemb_P = (const float*)d_in[18];
    const float *Wl_P = (const float*)d_in[19], *bl_P = (const float*)d_in[20];
    const float *Wr_P = (const float*)d_in[21], *br_P = (const float*)d_in[22];
    const float *We_P = (const float*)d_in[23], *att_P = (const float*)d_in[24], *bias_P = (const float*)d_in[25];
    const float *Win = (const float*)d_in[26], *b_in = (const float*)d_in[27];
    const float *Wout = (const float*)d_in[28], *bout = (const float*)d_in[29];
    const float *Wq = (const float*)d_in[30], *bq = (const float*)d_in[31];
    const float *Wk = (const float*)d_in[32], *bk = (const float*)d_in[33];
    const float *Wv = (const float*)d_in[34], *bv = (const float*)d_in[35];
    const float *W1 = (const float*)d_in[36], *b1 = (const float*)d_in[37];
    const float *W2 = (const float*)d_in[38], *b2 = (const float*)d_in[39];

    const int N_L = in_sizes[1] / 3;
    const int N_P = in_sizes[3] / 3;
    const int E_L = in_sizes[4] / 2;
    const int E_P = in_sizes[5] / 2;
    const int E_X = in_sizes[6];
    const int D_L = in_sizes[0] / N_L;
    const int D_P = in_sizes[2] / N_P;

    // workspace layout (f32)
    float* ws   = (float*)d_ws;
    float* s_L  = ws;                             // N_L*96
    float* s_P  = s_L + (size_t)N_L * 96;         // N_P*96
    float* xl   = s_P + (size_t)N_P * 96;         // N_P*96 (shared L/P; later qn)
    float* xr   = xl + (size_t)N_P * 96;          // N_P*96 (later kn)
    float* agg  = xr + (size_t)N_P * 96;          // N_P*96 (later vn)
    float* elog = agg + (size_t)N_P * 96;         // max(E_L,E_P); reused as clog later
    float* mbuf = elog + (size_t)(E_P > E_L ? E_P : E_L);  // N_P
    float* dbuf = mbuf + (size_t)N_P;             // N_P
    float* clog = elog;                           // E_X <= E_P: reuse
    float* csc  = dbuf + (size_t)N_P;             // 2

    const float NEG_INF = -__builtin_inff();

    // ---------------- L encoder ----------------
    embed_kernel<<<N_L, 96, 0, stream>>>(x_L, Wemb_L, bemb_L, s_L, D_L);
    lin_kernel<<<N_L, 96, 0, stream>>>(s_L, Wl_L, bl_L, Wr_L, br_L, xl, xr);
    fill_kernel<<<cdiv(N_L, 256), 256, 0, stream>>>(mbuf, NEG_INF, N_L);
    fill_kernel<<<cdiv(N_L, 256), 256, 0, stream>>>(dbuf, 0.f, N_L);
    fill_kernel<<<cdiv(N_L * 96, 256), 256, 0, stream>>>(agg, 0.f, N_L * 96);
    edge_logit_kernel<<<cdiv(E_L, 256), 256, 0, stream>>>(edge_L, edge_L + E_L, pos_L, xl, xr,
                                                          We_L, att_L, elog, mbuf, E_L);
    edge_denom_kernel<<<cdiv(E_L, 256), 256, 0, stream>>>(edge_L + E_L, elog, mbuf, dbuf, E_L);
    edge_scatter_kernel<<<E_L / 4, 384, 0, stream>>>(edge_L, edge_L + E_L, elog, mbuf, dbuf, xl, agg, E_L);
    node_update_kernel<<<cdiv(N_L * 96, 256), 256, 0, stream>>>(s_L, agg, bias_L, N_L * 96);

    // ---------------- P encoder ----------------
    embed_kernel<<<N_P, 96, 0, stream>>>(x_P, Wemb_P, bemb_P, s_P, D_P);
    lin_kernel<<<N_P, 96, 0, stream>>>(s_P, Wl_P, bl_P, Wr_P, br_P, xl, xr);
    fill_kernel<<<cdiv(N_P, 256), 256, 0, stream>>>(mbuf, NEG_INF, N_P);
    fill_kernel<<<cdiv(N_P, 256), 256, 0, stream>>>(dbuf, 0.f, N_P);
    fill_kernel<<<cdiv(N_P * 96, 256), 256, 0, stream>>>(agg, 0.f, N_P * 96);
    edge_logit_kernel<<<cdiv(E_P, 256), 256, 0, stream>>>(edge_P, edge_P + E_P, pos_P, xl, xr,
                                                          We_P, att_P, elog, mbuf, E_P);
    edge_denom_kernel<<<cdiv(E_P, 256), 256, 0, stream>>>(edge_P + E_P, elog, mbuf, dbuf, E_P);
    edge_scatter_kernel<<<E_P / 4, 384, 0, stream>>>(edge_P, edge_P + E_P, elog, mbuf, dbuf, xl, agg, E_P);
    node_update_kernel<<<cdiv(N_P * 96, 256), 256, 0, stream>>>(s_P, agg, bias_P, N_P * 96);

    // ---------------- SSM block (L) ----------------
    ssm_kernel<<<N_L, 192, 0, stream>>>(s_L, Win, b_in, Wout, bout);

    // ---------------- cross attention ----------------
    lin_kernel<<<N_L, 96, 0, stream>>>(s_L, Wq, bq, nullptr, nullptr, xl, nullptr);  // qn -> xl
    lin_kernel<<<N_P, 96, 0, stream>>>(s_P, Wk, bk, Wv, bv, xr, agg);                // kn -> xr, vn -> agg
    fill_kernel<<<1, 64, 0, stream>>>(csc, NEG_INF, 1);
    fill_kernel<<<1, 64, 0, stream>>>(csc + 1, 0.f, 1);
    cross_logit_kernel<<<cdiv(E_X, 256), 256, 0, stream>>>(csrc, ctgt, xl, xr, clog, csc, E_X);
    cross_denom_kernel<<<cdiv(E_X, 256), 256, 0, stream>>>(clog, csc, E_X);
    cross_scatter_kernel<<<E_X / 4, 384, 0, stream>>>(csrc, ctgt, clog, csc, agg, s_L, E_X);

    // ---------------- head ----------------
    head_kernel<<<N_L, 96, 0, stream>>>(s_L, W1, b1, W2, b2, (float*)d_out);
}

// Round 3
// 979.181 us; speedup vs baseline: 1.2466x; 1.2466x over previous
//
#include <hip/hip_runtime.h>

__device__ __forceinline__ float silu_f(float x) { return x / (1.f + __expf(-x)); }

// float atomic max via int/uint ordering trick (NaN-free values)
__device__ __forceinline__ void atomicMaxF(float* addr, float val) {
    if (val >= 0.f) atomicMax((int*)addr, __float_as_int(val));
    else            atomicMin((unsigned int*)addr, __float_as_uint(val));
}

__global__ void fill_f(float* __restrict__ p, float v, int n) {
    int i = blockIdx.x * blockDim.x + threadIdx.x;
    if (i < n) p[i] = v;
}
__global__ void fill_i(int* __restrict__ p, int v, int n) {
    int i = blockIdx.x * blockDim.x + threadIdx.x;
    if (i < n) p[i] = v;
}

__global__ void hist_kernel(const int* __restrict__ tgt, int* __restrict__ count, int E) {
    int e = blockIdx.x * blockDim.x + threadIdx.x;
    if (e < E) atomicAdd(&count[tgt[e]], 1);
}

// single-block exclusive scan: count[0..n) -> rowptr[0..n], cursor[0..n)
__global__ __launch_bounds__(1024) void scan_kernel(const int* __restrict__ count,
                                                    int* __restrict__ rowptr,
                                                    int* __restrict__ cursor, int n) {
    __shared__ int part[1024];
    int t = threadIdx.x;
    int chunk = (n + 1023) >> 10;
    int beg = t * chunk, end = min(beg + chunk, n);
    int s = 0;
    for (int i = beg; i < end; ++i) s += count[i];
    part[t] = s; __syncthreads();
    for (int off = 1; off < 1024; off <<= 1) {
        int v = (t >= off) ? part[t - off] : 0;
        __syncthreads();
        part[t] += v;
        __syncthreads();
    }
    int run = (t == 0) ? 0 : part[t - 1];
    for (int i = beg; i < end; ++i) { int c = count[i]; rowptr[i] = run; cursor[i] = run; run += c; }
    if (end == n) rowptr[n] = run;
}

// ---------- row-blocked dense kernels (192 thr = 3 waves; half = t/96 handles 8 rows) ----------

// s[n,h] = silu(x[n,:]@W + b); D <= 167
__global__ __launch_bounds__(192) void embed2_kernel(const float* __restrict__ x,
        const float* __restrict__ W, const float* __restrict__ b,
        float* __restrict__ s, int N, int D) {
    __shared__ float xs[16 * 167];
    int t = threadIdx.x, half = t / 96, h = t - half * 96;
    int n0 = blockIdx.x * 16;
    for (int i = t; i < 16 * D; i += 192) {
        int r = i / D, d = i - r * D, nn = n0 + r;
        xs[i] = (nn < N) ? x[(size_t)nn * D + d] : 0.f;
    }
    __syncthreads();
    float acc[8]; float bb = b[h];
#pragma unroll
    for (int r = 0; r < 8; ++r) acc[r] = bb;
    const float* xp = &xs[half * 8 * D];
    for (int d = 0; d < D; ++d) {
        float w = W[d * 96 + h];
#pragma unroll
        for (int r = 0; r < 8; ++r) acc[r] += xp[r * D + d] * w;
    }
#pragma unroll
    for (int r = 0; r < 8; ++r) {
        int nn = n0 + half * 8 + r;
        if (nn < N) s[(size_t)nn * 96 + h] = silu_f(acc[r]);
    }
}

// one or two HxH linears, row-blocked
__global__ __launch_bounds__(192) void lin2_kernel(const float* __restrict__ s,
        const float* __restrict__ W1, const float* __restrict__ b1,
        const float* __restrict__ W2, const float* __restrict__ b2,
        float* __restrict__ o1, float* __restrict__ o2, int N) {
    __shared__ float xs[16 * 96];
    int t = threadIdx.x, half = t / 96, h = t - half * 96;
    int n0 = blockIdx.x * 16;
    for (int i = t; i < 16 * 96; i += 192) {
        int r = i / 96, c = i - r * 96, nn = n0 + r;
        xs[i] = (nn < N) ? s[(size_t)nn * 96 + c] : 0.f;
    }
    __syncthreads();
    const float* xp = &xs[half * 8 * 96];
    float a1[8], a2[8];
    float bb1 = b1[h];
#pragma unroll
    for (int r = 0; r < 8; ++r) a1[r] = bb1;
    if (W2) {
        float bb2 = b2[h];
#pragma unroll
        for (int r = 0; r < 8; ++r) a2[r] = bb2;
        for (int k = 0; k < 96; ++k) {
            float w1 = W1[k * 96 + h], w2 = W2[k * 96 + h];
#pragma unroll
            for (int r = 0; r < 8; ++r) { float v = xp[r * 96 + k]; a1[r] += v * w1; a2[r] += v * w2; }
        }
#pragma unroll
        for (int r = 0; r < 8; ++r) {
            int nn = n0 + half * 8 + r;
            if (nn < N) { o1[(size_t)nn * 96 + h] = a1[r]; o2[(size_t)nn * 96 + h] = a2[r]; }
        }
    } else {
        for (int k = 0; k < 96; ++k) {
            float w1 = W1[k * 96 + h];
#pragma unroll
            for (int r = 0; r < 8; ++r) a1[r] += xp[r * 96 + k] * w1;
        }
#pragma unroll
        for (int r = 0; r < 8; ++r) {
            int nn = n0 + half * 8 + r;
            if (nn < N) o1[(size_t)nn * 96 + h] = a1[r];
        }
    }
}

// per-edge GATv2 logit; writes result into CSR slot via cursor
__global__ __launch_bounds__(256) void edge_logit_csr_kernel(const int* __restrict__ src,
        const int* __restrict__ tgt, const float* __restrict__ pos,
        const float* __restrict__ xl, const float* __restrict__ xr,
        const float* __restrict__ We, const float* __restrict__ att,
        int* __restrict__ cursor, float* __restrict__ elog_s, int* __restrict__ src_s, int E) {
    __shared__ float sWe[16 * 96];
    __shared__ float sAtt[96];
    for (int i = threadIdx.x; i < 16 * 96; i += blockDim.x) sWe[i] = We[i];
    for (int i = threadIdx.x; i < 96; i += blockDim.x) sAtt[i] = att[i];
    __syncthreads();
    int e = blockIdx.x * blockDim.x + threadIdx.x;
    if (e >= E) return;
    int si = src[e], ti = tgt[e];
    float dx = pos[si * 3 + 0] - pos[ti * 3 + 0];
    float dy = pos[si * 3 + 1] - pos[ti * 3 + 1];
    float dz = pos[si * 3 + 2] - pos[ti * 3 + 2];
    float d = sqrtf(dx * dx + dy * dy + dz * dz);
    float rbf[16];
#pragma unroll
    for (int g = 0; g < 16; ++g) {
        float tt = d - (10.f / 15.f) * (float)g;
        rbf[g] = __expf(-1.125f * tt * tt);
    }
    const float4* xl4 = (const float4*)(xl + (size_t)si * 96);
    const float4* xr4 = (const float4*)(xr + (size_t)ti * 96);
    float logit = 0.f;
#pragma unroll 6
    for (int hh = 0; hh < 24; ++hh) {
        float4 a = xl4[hh], b = xr4[hh];
        float v0 = a.x + b.x, v1 = a.y + b.y, v2 = a.z + b.z, v3 = a.w + b.w;
        int h = hh * 4;
#pragma unroll
        for (int g = 0; g < 16; ++g) {
            float r = rbf[g];
            const float* wp = &sWe[g * 96 + h];
            v0 += r * wp[0]; v1 += r * wp[1]; v2 += r * wp[2]; v3 += r * wp[3];
        }
        v0 = v0 >= 0.f ? v0 : 0.2f * v0;
        v1 = v1 >= 0.f ? v1 : 0.2f * v1;
        v2 = v2 >= 0.f ? v2 : 0.2f * v2;
        v3 = v3 >= 0.f ? v3 : 0.2f * v3;
        logit += v0 * sAtt[h] + v1 * sAtt[h + 1] + v2 * sAtt[h + 2] + v3 * sAtt[h + 3];
    }
    int p = atomicAdd(&cursor[ti], 1);
    elog_s[p] = logit;
    src_s[p] = si;
}

// node-major segment softmax + aggregate + silu update; 2 nodes per 192-thr block
__global__ __launch_bounds__(192) void gat_agg_kernel(const int* __restrict__ rowptr,
        const int* __restrict__ src_s, const float* __restrict__ elog_s,
        const float* __restrict__ xl, const float* __restrict__ bias,
        float* __restrict__ s, int N) {
    int t = threadIdx.x;
    int n = blockIdx.x * 2 + t / 96;
    int h = t % 96;
    if (n >= N) return;
    int beg = rowptr[n], end = rowptr[n + 1];
    float agg = 0.f;
    if (end > beg) {
        float mx = -3.4e38f;
        for (int j = beg; j < end; ++j) mx = fmaxf(mx, elog_s[j]);
        float dsum = 0.f, acc = 0.f;
        for (int j = beg; j < end; ++j) {
            float w = __expf(elog_s[j] - mx);
            dsum += w;
            acc += w * xl[(size_t)src_s[j] * 96 + h];
        }
        agg = acc / dsum;
    }
    s[(size_t)n * 96 + h] += silu_f(agg + bias[h]);
}

// s_L += silu(s_L@Win + b_in)[:, :192] @ Wout + bout; 4 rows per 192-thr block
__global__ __launch_bounds__(192) void ssm2_kernel(float* __restrict__ sL,
        const float* __restrict__ Win, const float* __restrict__ b_in,
        const float* __restrict__ Wout, const float* __restrict__ bout, int N) {
    __shared__ float row[4 * 96];
    __shared__ float u[4 * 192];
    __shared__ float pu[4 * 96];
    int t = threadIdx.x;
    int n0 = blockIdx.x * 4;
    for (int i = t; i < 4 * 96; i += 192) {
        int r = i / 96, c = i - r * 96, nn = n0 + r;
        row[i] = (nn < N) ? sL[(size_t)nn * 96 + c] : 0.f;
    }
    __syncthreads();
    float acc[4]; float bb = b_in[t];
#pragma unroll
    for (int r = 0; r < 4; ++r) acc[r] = bb;
    for (int k = 0; k < 96; ++k) {
        float w = Win[k * 384 + t];
#pragma unroll
        for (int r = 0; r < 4; ++r) acc[r] += row[r * 96 + k] * w;
    }
#pragma unroll
    for (int r = 0; r < 4; ++r) u[r * 192 + t] = silu_f(acc[r]);
    __syncthreads();
    int half = t / 96, h = t - half * 96;
    float d[4] = {0.f, 0.f, 0.f, 0.f};
    int j0 = half * 96;
    for (int j = j0; j < j0 + 96; ++j) {
        float w = Wout[j * 96 + h];
#pragma unroll
        for (int r = 0; r < 4; ++r) d[r] += u[r * 192 + j] * w;
    }
    if (half == 1) {
#pragma unroll
        for (int r = 0; r < 4; ++r) pu[r * 96 + h] = d[r];
    }
    __syncthreads();
    if (half == 0) {
        float bo = bout[h];
#pragma unroll
        for (int r = 0; r < 4; ++r) {
            int nn = n0 + r;
            if (nn < N) sL[(size_t)nn * 96 + h] = row[r * 96 + h] + bo + d[r] + pu[r * 96 + h];
        }
    }
}

// cross-edge q.k/8 into CSR slot + global max reduce
__global__ __launch_bounds__(256) void cross_logit_csr_kernel(const int* __restrict__ csrc,
        const int* __restrict__ ctgt, const float* __restrict__ qn, const float* __restrict__ kn,
        int* __restrict__ cursor, float* __restrict__ clog_s, int* __restrict__ csrc_s,
        float* __restrict__ csc, int E) {
    int e = blockIdx.x * blockDim.x + threadIdx.x;
    float logit = -3.4e38f;
    if (e < E) {
        int si = csrc[e], ti = ctgt[e];
        const float4* q4 = (const float4*)(qn + (size_t)ti * 96);
        const float4* k4 = (const float4*)(kn + (size_t)si * 96);
        float acc = 0.f;
#pragma unroll
        for (int i = 0; i < 24; ++i) {
            float4 a = q4[i], b = k4[i];
            acc += a.x * b.x + a.y * b.y + a.z * b.z + a.w * b.w;
        }
        logit = acc * 0.125f;
        int p = atomicAdd(&cursor[ti], 1);
        clog_s[p] = logit;
        csrc_s[p] = si;
    }
    __shared__ float red[256];
    red[threadIdx.x] = logit; __syncthreads();
    for (int s = 128; s > 0; s >>= 1) {
        if (threadIdx.x < s) red[threadIdx.x] = fmaxf(red[threadIdx.x], red[threadIdx.x + s]);
        __syncthreads();
    }
    if (threadIdx.x == 0) atomicMaxF(&csc[0], red[0]);
}

__global__ __launch_bounds__(256) void cross_denom_kernel(const float* __restrict__ clog_s,
                                                          float* __restrict__ csc, int E) {
    int e = blockIdx.x * blockDim.x + threadIdx.x;
    float a = 0.f;
    float mg = csc[0];
    if (e < E) a = __expf(clog_s[e] - mg);
    __shared__ float red[256];
    red[threadIdx.x] = a; __syncthreads();
    for (int s = 128; s > 0; s >>= 1) {
        if (threadIdx.x < s) red[threadIdx.x] += red[threadIdx.x + s];
        __syncthreads();
    }
    if (threadIdx.x == 0) atomicAdd(&csc[1], red[0]);
}

// node-major cross-attention apply; 2 nodes per 192-thr block
__global__ __launch_bounds__(192) void cross_apply_kernel(const int* __restrict__ rowptr,
        const int* __restrict__ csrc_s, const float* __restrict__ clog_s,
        const float* __restrict__ vn, const float* __restrict__ csc,
        float* __restrict__ sL, int N) {
    int t = threadIdx.x;
    int n = blockIdx.x * 2 + t / 96;
    int h = t % 96;
    if (n >= N) return;
    int beg = rowptr[n], end = rowptr[n + 1];
    if (beg == end) return;
    float mx = csc[0], invd = 1.f / csc[1];
    float acc = 0.f;
    for (int j = beg; j < end; ++j)
        acc += __expf(clog_s[j] - mx) * vn[(size_t)csrc_s[j] * 96 + h];
    sL[(size_t)n * 96 + h] += acc * invd;
}

// out = silu(sL@W1+b1)@W2+b2 ; 16 rows per 192-thr block
__global__ __launch_bounds__(192) void head2_kernel(const float* __restrict__ sL,
        const float* __restrict__ W1, const float* __restrict__ b1,
        const float* __restrict__ W2, const float* __restrict__ b2,
        float* __restrict__ out, int N) {
    __shared__ float buf[16 * 96];
    int t = threadIdx.x, half = t / 96, h = t - half * 96;
    int n0 = blockIdx.x * 16;
    for (int i = t; i < 16 * 96; i += 192) {
        int r = i / 96, c = i - r * 96, nn = n0 + r;
        buf[i] = (nn < N) ? sL[(size_t)nn * 96 + c] : 0.f;
    }
    __syncthreads();
    int rbase = half * 8;
    float a[8]; float bb = b1[h];
#pragma unroll
    for (int r = 0; r < 8; ++r) a[r] = bb;
    for (int k = 0; k < 96; ++k) {
        float w = W1[k * 96 + h];
#pragma unroll
        for (int r = 0; r < 8; ++r) a[r] += buf[(rbase + r) * 96 + k] * w;
    }
    __syncthreads();
#pragma unroll
    for (int r = 0; r < 8; ++r) buf[(rbase + r) * 96 + h] = silu_f(a[r]);
    __syncthreads();
    if (t < 48) {
        int r = t / 3, c = t - r * 3;
        float o = b2[c];
        for (int j = 0; j < 96; ++j) o += buf[r * 96 + j] * W2[j * 3 + c];
        int nn = n0 + r;
        if (nn < N) out[nn * 3 + c] = o;
    }
}

static inline int cdiv(int a, int b) { return (a + b - 1) / b; }

extern "C" void kernel_launch(void* const* d_in, const int* in_sizes, int n_in,
                              void* d_out, int out_size, void* d_ws, size_t ws_size,
                              hipStream_t stream) {
    const float* x_L   = (const float*)d_in[0];
    const float* pos_L = (const float*)d_in[1];
    const float* x_P   = (const float*)d_in[2];
    const float* pos_P = (const float*)d_in[3];
    const int* edge_L = (const int*)d_in[4];
    const int* edge_P = (const int*)d_in[5];
    const int* csrc   = (const int*)d_in[6];
    const int* ctgt   = (const int*)d_in[7];
    const float *Wemb_L = (const float*)d_in[8],  *bemb_L = (const float*)d_in[9];
    const float *Wl_L = (const float*)d_in[10], *bl_L = (const float*)d_in[11];
    const float *Wr_L = (const float*)d_in[12], *br_L = (const float*)d_in[13];
    const float *We_L = (const float*)d_in[14], *att_L = (const float*)d_in[15], *bias_L = (const float*)d_in[16];
    const float *Wemb_P = (const float*)d_in[17], *bemb_P = (const float*)d_in[18];
    const float *Wl_P = (const float*)d_in[19], *bl_P = (const float*)d_in[20];
    const float *Wr_P = (const float*)d_in[21], *br_P = (const float*)d_in[22];
    const float *We_P = (const float*)d_in[23], *att_P = (const float*)d_in[24], *bias_P = (const float*)d_in[25];
    const float *Win = (const float*)d_in[26], *b_in = (const float*)d_in[27];
    const float *Wout = (const float*)d_in[28], *bout = (const float*)d_in[29];
    const float *Wq = (const float*)d_in[30], *bq = (const float*)d_in[31];
    const float *Wk = (const float*)d_in[32], *bk = (const float*)d_in[33];
    const float *Wv = (const float*)d_in[34], *bv = (const float*)d_in[35];
    const float *W1 = (const float*)d_in[36], *b1 = (const float*)d_in[37];
    const float *W2 = (const float*)d_in[38], *b2 = (const float*)d_in[39];

    const int N_L = in_sizes[1] / 3;
    const int N_P = in_sizes[3] / 3;
    const int E_L = in_sizes[4] / 2;
    const int E_P = in_sizes[5] / 2;
    const int E_X = in_sizes[6];
    const int D_L = in_sizes[0] / N_L;
    const int D_P = in_sizes[2] / N_P;
    const int Emax = (E_L > E_P ? E_L : E_P) > E_X ? (E_L > E_P ? E_L : E_P) : E_X;
    const int Nmax = N_L > N_P ? N_L : N_P;

    // workspace layout (4B units)
    float* ws    = (float*)d_ws;
    float* s_L   = ws;                                   // N_L*96
    float* s_P   = s_L + (size_t)N_L * 96;               // N_P*96
    float* xl    = s_P + (size_t)N_P * 96;               // N_P*96 (later qn)
    float* xr    = xl + (size_t)N_P * 96;                // N_P*96 (later kn)
    float* vn    = xr + (size_t)N_P * 96;                // N_P*96
    float* elog_s = vn + (size_t)N_P * 96;               // Emax (later clog_s)
    int*   src_s  = (int*)(elog_s + (size_t)Emax);       // Emax (later csrc_s)
    int*   rowptr = src_s + (size_t)Emax;                // Nmax+1
    int*   count  = rowptr + (size_t)Nmax + 1;           // Nmax
    int*   cursor = count + (size_t)Nmax;                // Nmax
    float* csc    = (float*)(cursor + (size_t)Nmax);     // 2

    const float NEG = -3.4e38f;

    // ---------------- L encoder ----------------
    embed2_kernel<<<cdiv(N_L, 16), 192, 0, stream>>>(x_L, Wemb_L, bemb_L, s_L, N_L, D_L);
    lin2_kernel<<<cdiv(N_L, 16), 192, 0, stream>>>(s_L, Wl_L, bl_L, Wr_L, br_L, xl, xr, N_L);
    fill_i<<<cdiv(N_L, 256), 256, 0, stream>>>(count, 0, N_L);
    hist_kernel<<<cdiv(E_L, 256), 256, 0, stream>>>(edge_L + E_L, count, E_L);
    scan_kernel<<<1, 1024, 0, stream>>>(count, rowptr, cursor, N_L);
    edge_logit_csr_kernel<<<cdiv(E_L, 256), 256, 0, stream>>>(edge_L, edge_L + E_L, pos_L,
        xl, xr, We_L, att_L, cursor, elog_s, src_s, E_L);
    gat_agg_kernel<<<cdiv(N_L, 2), 192, 0, stream>>>(rowptr, src_s, elog_s, xl, bias_L, s_L, N_L);

    // ---------------- P encoder ----------------
    embed2_kernel<<<cdiv(N_P, 16), 192, 0, stream>>>(x_P, Wemb_P, bemb_P, s_P, N_P, D_P);
    lin2_kernel<<<cdiv(N_P, 16), 192, 0, stream>>>(s_P, Wl_P, bl_P, Wr_P, br_P, xl, xr, N_P);
    fill_i<<<cdiv(N_P, 256), 256, 0, stream>>>(count, 0, N_P);
    hist_kernel<<<cdiv(E_P, 256), 256, 0, stream>>>(edge_P + E_P, count, E_P);
    scan_kernel<<<1, 1024, 0, stream>>>(count, rowptr, cursor, N_P);
    edge_logit_csr_kernel<<<cdiv(E_P, 256), 256, 0, stream>>>(edge_P, edge_P + E_P, pos_P,
        xl, xr, We_P, att_P, cursor, elog_s, src_s, E_P);
    gat_agg_kernel<<<cdiv(N_P, 2), 192, 0, stream>>>(rowptr, src_s, elog_s, xl, bias_P, s_P, N_P);

    // ---------------- SSM block (L) ----------------
    ssm2_kernel<<<cdiv(N_L, 4), 192, 0, stream>>>(s_L, Win, b_in, Wout, bout, N_L);

    // ---------------- cross attention ----------------
    lin2_kernel<<<cdiv(N_L, 16), 192, 0, stream>>>(s_L, Wq, bq, nullptr, nullptr, xl, nullptr, N_L);
    lin2_kernel<<<cdiv(N_P, 16), 192, 0, stream>>>(s_P, Wk, bk, Wv, bv, xr, vn, N_P);
    fill_i<<<cdiv(N_L, 256), 256, 0, stream>>>(count, 0, N_L);
    hist_kernel<<<cdiv(E_X, 256), 256, 0, stream>>>(ctgt, count, E_X);
    scan_kernel<<<1, 1024, 0, stream>>>(count, rowptr, cursor, N_L);
    fill_f<<<1, 64, 0, stream>>>(csc, NEG, 1);
    fill_f<<<1, 64, 0, stream>>>(csc + 1, 0.f, 1);
    cross_logit_csr_kernel<<<cdiv(E_X, 256), 256, 0, stream>>>(csrc, ctgt, xl, xr,
        cursor, elog_s, src_s, csc, E_X);
    cross_denom_kernel<<<cdiv(E_X, 256), 256, 0, stream>>>(elog_s, csc, E_X);
    cross_apply_kernel<<<cdiv(N_L, 2), 192, 0, stream>>>(rowptr, src_s, elog_s, vn, csc, s_L, N_L);

    // ---------------- head ----------------
    head2_kernel<<<cdiv(N_L, 16), 192, 0, stream>>>(s_L, W1, b1, W2, b2, (float*)d_out, N_L);
}

// Round 4
// 949.113 us; speedup vs baseline: 1.2861x; 1.0317x over previous
//
#include <hip/hip_runtime.h>

__device__ __forceinline__ float silu_f(float x) { return x / (1.f + __expf(-x)); }

// float atomic max via int/uint ordering trick (NaN-free values)
__device__ __forceinline__ void atomicMaxF(float* addr, float val) {
    if (val >= 0.f) atomicMax((int*)addr, __float_as_int(val));
    else            atomicMin((unsigned int*)addr, __float_as_uint(val));
}

__global__ void fill_f(float* __restrict__ p, float v, int n) {
    int i = blockIdx.x * blockDim.x + threadIdx.x;
    if (i < n) p[i] = v;
}
__global__ void fill_i(int* __restrict__ p, int v, int n) {
    int i = blockIdx.x * blockDim.x + threadIdx.x;
    if (i < n) p[i] = v;
}

__global__ void hist_kernel(const int* __restrict__ tgt, int* __restrict__ count, int E) {
    int e = blockIdx.x * blockDim.x + threadIdx.x;
    if (e < E) atomicAdd(&count[tgt[e]], 1);
}

// single-block exclusive scan: count[0..n) -> rowptr[0..n], cursor[0..n)
__global__ __launch_bounds__(1024) void scan_kernel(const int* __restrict__ count,
                                                    int* __restrict__ rowptr,
                                                    int* __restrict__ cursor, int n) {
    __shared__ int part[1024];
    int t = threadIdx.x;
    int chunk = (n + 1023) >> 10;
    int beg = t * chunk, end = min(beg + chunk, n);
    int s = 0;
    for (int i = beg; i < end; ++i) s += count[i];
    part[t] = s; __syncthreads();
    for (int off = 1; off < 1024; off <<= 1) {
        int v = (t >= off) ? part[t - off] : 0;
        __syncthreads();
        part[t] += v;
        __syncthreads();
    }
    int run = (t == 0) ? 0 : part[t - 1];
    for (int i = beg; i < end; ++i) { int c = count[i]; rowptr[i] = run; cursor[i] = run; run += c; }
    if (end == n) rowptr[n] = run;
}

// GAT pre-pass: scatter (src, dist) into CSR slot of tgt
__global__ __launch_bounds__(256) void gat_pre_kernel(const int* __restrict__ src,
        const int* __restrict__ tgt, const float* __restrict__ pos,
        int* __restrict__ cursor, int2* __restrict__ sd, int E) {
    int e = blockIdx.x * blockDim.x + threadIdx.x;
    if (e >= E) return;
    int si = src[e], ti = tgt[e];
    float dx = pos[si * 3 + 0] - pos[ti * 3 + 0];
    float dy = pos[si * 3 + 1] - pos[ti * 3 + 1];
    float dz = pos[si * 3 + 2] - pos[ti * 3 + 2];
    float dist = sqrtf(dx * dx + dy * dy + dz * dz);
    int p = atomicAdd(&cursor[ti], 1);
    sd[p] = make_int2(si, __float_as_int(dist));
}

// cross pre-pass: scatter src into CSR slot of tgt
__global__ __launch_bounds__(256) void cross_pre_kernel(const int* __restrict__ csrc,
        const int* __restrict__ ctgt, int* __restrict__ cursor, int* __restrict__ csrc_s, int E) {
    int e = blockIdx.x * blockDim.x + threadIdx.x;
    if (e >= E) return;
    int p = atomicAdd(&cursor[ctgt[e]], 1);
    csrc_s[p] = csrc[e];
}

// Fused GATv2: per-node online-softmax over CSR edges, single xl gather per edge.
// One wave per node; lane l owns h=l and h=64+l (lanes 0..31 only for the latter).
__global__ __launch_bounds__(256) void gat_fused_kernel(const int* __restrict__ rowptr,
        const int2* __restrict__ sd, const float* __restrict__ xl, const float* __restrict__ xr,
        const float* __restrict__ We, const float* __restrict__ att,
        const float* __restrict__ bias, float* __restrict__ s, int N) {
    int lane = threadIdx.x & 63;
    int n = __builtin_amdgcn_readfirstlane(blockIdx.x * 4 + (threadIdx.x >> 6));
    if (n >= N) return;
    int h0 = lane, h1 = 64 + lane;
    bool has1 = lane < 32;
    float w0[16], w1[16];
#pragma unroll
    for (int g = 0; g < 16; ++g) {
        w0[g] = We[g * 96 + h0];
        w1[g] = has1 ? We[g * 96 + h1] : 0.f;
    }
    float att0 = att[h0], att1 = has1 ? att[h1] : 0.f;
    float xr0 = xr[(size_t)n * 96 + h0];
    float xr1 = has1 ? xr[(size_t)n * 96 + h1] : 0.f;
    int beg = rowptr[n], end = rowptr[n + 1];
    float m = -3.4e38f, d = 0.f, a0 = 0.f, a1 = 0.f;
    for (int j = beg; j < end; ++j) {
        int2 e = sd[j];
        int si = e.x;
        float dist = __int_as_float(e.y);
        float xl0 = xl[(size_t)si * 96 + h0];
        float xl1 = has1 ? xl[(size_t)si * 96 + h1] : 0.f;
        float v0 = xl0 + xr0, v1 = xl1 + xr1;
#pragma unroll
        for (int g = 0; g < 16; ++g) {
            float tt = dist - 0.66666667f * (float)g;
            float r = __expf(-1.125f * tt * tt);
            v0 += r * w0[g];
            v1 += r * w1[g];
        }
        v0 = v0 >= 0.f ? v0 : 0.2f * v0;
        v1 = v1 >= 0.f ? v1 : 0.2f * v1;
        float t = v0 * att0 + v1 * att1;
#pragma unroll
        for (int off = 1; off < 64; off <<= 1) t += __shfl_xor(t, off, 64);
        float nm = fmaxf(m, t);
        float sc = __expf(m - nm);
        float w = __expf(t - nm);
        d = d * sc + w;
        a0 = a0 * sc + w * xl0;
        a1 = a1 * sc + w * xl1;
        m = nm;
    }
    float agg0 = (d > 0.f) ? a0 / d : 0.f;
    float agg1 = (d > 0.f) ? a1 / d : 0.f;
    s[(size_t)n * 96 + h0] += silu_f(agg0 + bias[h0]);
    if (has1) s[(size_t)n * 96 + h1] += silu_f(agg1 + bias[h1]);
}

// cross logits node-major: q in registers, gather k rows once; write logit to CSR slot
__global__ __launch_bounds__(256) void cross_logit_node_kernel(const int* __restrict__ rowptr,
        const int* __restrict__ csrc_s, const float* __restrict__ qn, const float* __restrict__ kn,
        float* __restrict__ clog_s, float* __restrict__ csc, int N) {
    int lane = threadIdx.x & 63;
    int n = __builtin_amdgcn_readfirstlane(blockIdx.x * 4 + (threadIdx.x >> 6));
    if (n >= N) return;
    int h0 = lane, h1 = 64 + lane;
    bool has1 = lane < 32;
    float q0 = qn[(size_t)n * 96 + h0];
    float q1 = has1 ? qn[(size_t)n * 96 + h1] : 0.f;
    int beg = rowptr[n], end = rowptr[n + 1];
    float mx = -3.4e38f;
    for (int j = beg; j < end; ++j) {
        int si = csrc_s[j];
        float t = q0 * kn[(size_t)si * 96 + h0];
        if (has1) t += q1 * kn[(size_t)si * 96 + h1];
#pragma unroll
        for (int off = 1; off < 64; off <<= 1) t += __shfl_xor(t, off, 64);
        t *= 0.125f;
        if (lane == 0) clog_s[j] = t;
        mx = fmaxf(mx, t);
    }
    if (lane == 0 && end > beg) atomicMaxF(&csc[0], mx);
}

__global__ __launch_bounds__(256) void cross_denom_kernel(const float* __restrict__ clog_s,
                                                          float* __restrict__ csc, int E) {
    int e = blockIdx.x * blockDim.x + threadIdx.x;
    float a = 0.f;
    float mg = csc[0];
    if (e < E) a = __expf(clog_s[e] - mg);
    __shared__ float red[256];
    red[threadIdx.x] = a; __syncthreads();
    for (int s = 128; s > 0; s >>= 1) {
        if (threadIdx.x < s) red[threadIdx.x] += red[threadIdx.x + s];
        __syncthreads();
    }
    if (threadIdx.x == 0) atomicAdd(&csc[1], red[0]);
}

// cross apply node-major: gather vn rows once
__global__ __launch_bounds__(256) void cross_apply_node_kernel(const int* __restrict__ rowptr,
        const int* __restrict__ csrc_s, const float* __restrict__ clog_s,
        const float* __restrict__ vn, const float* __restrict__ csc,
        float* __restrict__ sL, int N) {
    int lane = threadIdx.x & 63;
    int n = __builtin_amdgcn_readfirstlane(blockIdx.x * 4 + (threadIdx.x >> 6));
    if (n >= N) return;
    int h0 = lane, h1 = 64 + lane;
    bool has1 = lane < 32;
    int beg = rowptr[n], end = rowptr[n + 1];
    if (beg == end) return;
    float M = csc[0], invD = 1.f / csc[1];
    float a0 = 0.f, a1 = 0.f;
    for (int j = beg; j < end; ++j) {
        int si = csrc_s[j];
        float w = __expf(clog_s[j] - M);
        a0 += w * vn[(size_t)si * 96 + h0];
        if (has1) a1 += w * vn[(size_t)si * 96 + h1];
    }
    sL[(size_t)n * 96 + h0] += a0 * invD;
    if (has1) sL[(size_t)n * 96 + h1] += a1 * invD;
}

// ---------- row-blocked dense kernels ----------

__global__ __launch_bounds__(192) void embed2_kernel(const float* __restrict__ x,
        const float* __restrict__ W, const float* __restrict__ b,
        float* __restrict__ s, int N, int D) {
    __shared__ float xs[16 * 167];
    int t = threadIdx.x, half = t / 96, h = t - half * 96;
    int n0 = blockIdx.x * 16;
    for (int i = t; i < 16 * D; i += 192) {
        int r = i / D, dd = i - r * D, nn = n0 + r;
        xs[i] = (nn < N) ? x[(size_t)nn * D + dd] : 0.f;
    }
    __syncthreads();
    float acc[8]; float bb = b[h];
#pragma unroll
    for (int r = 0; r < 8; ++r) acc[r] = bb;
    const float* xp = &xs[half * 8 * D];
    for (int dd = 0; dd < D; ++dd) {
        float w = W[dd * 96 + h];
#pragma unroll
        for (int r = 0; r < 8; ++r) acc[r] += xp[r * D + dd] * w;
    }
#pragma unroll
    for (int r = 0; r < 8; ++r) {
        int nn = n0 + half * 8 + r;
        if (nn < N) s[(size_t)nn * 96 + h] = silu_f(acc[r]);
    }
}

__global__ __launch_bounds__(192) void lin2_kernel(const float* __restrict__ s,
        const float* __restrict__ W1, const float* __restrict__ b1,
        const float* __restrict__ W2, const float* __restrict__ b2,
        float* __restrict__ o1, float* __restrict__ o2, int N) {
    __shared__ float xs[16 * 96];
    int t = threadIdx.x, half = t / 96, h = t - half * 96;
    int n0 = blockIdx.x * 16;
    for (int i = t; i < 16 * 96; i += 192) {
        int r = i / 96, c = i - r * 96, nn = n0 + r;
        xs[i] = (nn < N) ? s[(size_t)nn * 96 + c] : 0.f;
    }
    __syncthreads();
    const float* xp = &xs[half * 8 * 96];
    float a1[8], a2[8];
    float bb1 = b1[h];
#pragma unroll
    for (int r = 0; r < 8; ++r) a1[r] = bb1;
    if (W2) {
        float bb2 = b2[h];
#pragma unroll
        for (int r = 0; r < 8; ++r) a2[r] = bb2;
        for (int k = 0; k < 96; ++k) {
            float w1 = W1[k * 96 + h], w2 = W2[k * 96 + h];
#pragma unroll
            for (int r = 0; r < 8; ++r) { float v = xp[r * 96 + k]; a1[r] += v * w1; a2[r] += v * w2; }
        }
#pragma unroll
        for (int r = 0; r < 8; ++r) {
            int nn = n0 + half * 8 + r;
            if (nn < N) { o1[(size_t)nn * 96 + h] = a1[r]; o2[(size_t)nn * 96 + h] = a2[r]; }
        }
    } else {
        for (int k = 0; k < 96; ++k) {
            float w1 = W1[k * 96 + h];
#pragma unroll
            for (int r = 0; r < 8; ++r) a1[r] += xp[r * 96 + k] * w1;
        }
#pragma unroll
        for (int r = 0; r < 8; ++r) {
            int nn = n0 + half * 8 + r;
            if (nn < N) o1[(size_t)nn * 96 + h] = a1[r];
        }
    }
}

__global__ __launch_bounds__(192) void ssm2_kernel(float* __restrict__ sL,
        const float* __restrict__ Win, const float* __restrict__ b_in,
        const float* __restrict__ Wout, const float* __restrict__ bout, int N) {
    __shared__ float row[4 * 96];
    __shared__ float u[4 * 192];
    __shared__ float pu[4 * 96];
    int t = threadIdx.x;
    int n0 = blockIdx.x * 4;
    for (int i = t; i < 4 * 96; i += 192) {
        int r = i / 96, c = i - r * 96, nn = n0 + r;
        row[i] = (nn < N) ? sL[(size_t)nn * 96 + c] : 0.f;
    }
    __syncthreads();
    float acc[4]; float bb = b_in[t];
#pragma unroll
    for (int r = 0; r < 4; ++r) acc[r] = bb;
    for (int k = 0; k < 96; ++k) {
        float w = Win[k * 384 + t];
#pragma unroll
        for (int r = 0; r < 4; ++r) acc[r] += row[r * 96 + k] * w;
    }
#pragma unroll
    for (int r = 0; r < 4; ++r) u[r * 192 + t] = silu_f(acc[r]);
    __syncthreads();
    int half = t / 96, h = t - half * 96;
    float d[4] = {0.f, 0.f, 0.f, 0.f};
    int j0 = half * 96;
    for (int j = j0; j < j0 + 96; ++j) {
        float w = Wout[j * 96 + h];
#pragma unroll
        for (int r = 0; r < 4; ++r) d[r] += u[r * 192 + j] * w;
    }
    if (half == 1) {
#pragma unroll
        for (int r = 0; r < 4; ++r) pu[r * 96 + h] = d[r];
    }
    __syncthreads();
    if (half == 0) {
        float bo = bout[h];
#pragma unroll
        for (int r = 0; r < 4; ++r) {
            int nn = n0 + r;
            if (nn < N) sL[(size_t)nn * 96 + h] = row[r * 96 + h] + bo + d[r] + pu[r * 96 + h];
        }
    }
}

__global__ __launch_bounds__(192) void head2_kernel(const float* __restrict__ sL,
        const float* __restrict__ W1, const float* __restrict__ b1,
        const float* __restrict__ W2, const float* __restrict__ b2,
        float* __restrict__ out, int N) {
    __shared__ float buf[16 * 96];
    int t = threadIdx.x, half = t / 96, h = t - half * 96;
    int n0 = blockIdx.x * 16;
    for (int i = t; i < 16 * 96; i += 192) {
        int r = i / 96, c = i - r * 96, nn = n0 + r;
        buf[i] = (nn < N) ? sL[(size_t)nn * 96 + c] : 0.f;
    }
    __syncthreads();
    int rbase = half * 8;
    float a[8]; float bb = b1[h];
#pragma unroll
    for (int r = 0; r < 8; ++r) a[r] = bb;
    for (int k = 0; k < 96; ++k) {
        float w = W1[k * 96 + h];
#pragma unroll
        for (int r = 0; r < 8; ++r) a[r] += buf[(rbase + r) * 96 + k] * w;
    }
    __syncthreads();
#pragma unroll
    for (int r = 0; r < 8; ++r) buf[(rbase + r) * 96 + h] = silu_f(a[r]);
    __syncthreads();
    if (t < 48) {
        int r = t / 3, c = t - r * 3;
        float o = b2[c];
        for (int j = 0; j < 96; ++j) o += buf[r * 96 + j] * W2[j * 3 + c];
        int nn = n0 + r;
        if (nn < N) out[nn * 3 + c] = o;
    }
}

static inline int cdiv(int a, int b) { return (a + b - 1) / b; }

extern "C" void kernel_launch(void* const* d_in, const int* in_sizes, int n_in,
                              void* d_out, int out_size, void* d_ws, size_t ws_size,
                              hipStream_t stream) {
    const float* x_L   = (const float*)d_in[0];
    const float* pos_L = (const float*)d_in[1];
    const float* x_P   = (const float*)d_in[2];
    const float* pos_P = (const float*)d_in[3];
    const int* edge_L = (const int*)d_in[4];
    const int* edge_P = (const int*)d_in[5];
    const int* csrc   = (const int*)d_in[6];
    const int* ctgt   = (const int*)d_in[7];
    const float *Wemb_L = (const float*)d_in[8],  *bemb_L = (const float*)d_in[9];
    const float *Wl_L = (const float*)d_in[10], *bl_L = (const float*)d_in[11];
    const float *Wr_L = (const float*)d_in[12], *br_L = (const float*)d_in[13];
    const float *We_L = (const float*)d_in[14], *att_L = (const float*)d_in[15], *bias_L = (const float*)d_in[16];
    const float *Wemb_P = (const float*)d_in[17], *bemb_P = (const float*)d_in[18];
    const float *Wl_P = (const float*)d_in[19], *bl_P = (const float*)d_in[20];
    const float *Wr_P = (const float*)d_in[21], *br_P = (const float*)d_in[22];
    const float *We_P = (const float*)d_in[23], *att_P = (const float*)d_in[24], *bias_P = (const float*)d_in[25];
    const float *Win = (const float*)d_in[26], *b_in = (const float*)d_in[27];
    const float *Wout = (const float*)d_in[28], *bout = (const float*)d_in[29];
    const float *Wq = (const float*)d_in[30], *bq = (const float*)d_in[31];
    const float *Wk = (const float*)d_in[32], *bk = (const float*)d_in[33];
    const float *Wv = (const float*)d_in[34], *bv = (const float*)d_in[35];
    const float *W1 = (const float*)d_in[36], *b1 = (const float*)d_in[37];
    const float *W2 = (const float*)d_in[38], *b2 = (const float*)d_in[39];

    const int N_L = in_sizes[1] / 3;
    const int N_P = in_sizes[3] / 3;
    const int E_L = in_sizes[4] / 2;
    const int E_P = in_sizes[5] / 2;
    const int E_X = in_sizes[6];
    const int D_L = in_sizes[0] / N_L;
    const int D_P = in_sizes[2] / N_P;
    const int Emax = (E_L > E_P ? E_L : E_P) > E_X ? (E_L > E_P ? E_L : E_P) : E_X;
    const int Nmax = N_L > N_P ? N_L : N_P;

    // workspace layout (4B units)
    float* ws    = (float*)d_ws;
    float* s_L   = ws;                                   // N_L*96
    float* s_P   = s_L + (size_t)N_L * 96;               // N_P*96
    float* xl    = s_P + (size_t)N_P * 96;               // N_P*96 (later qn)
    float* xr    = xl + (size_t)N_P * 96;                // N_P*96 (later kn)
    float* vn    = xr + (size_t)N_P * 96;                // N_P*96
    int2*  sd    = (int2*)(vn + (size_t)N_P * 96);       // Emax int2
    int*   csrc_s = (int*)sd;                            // cross: Emax ints (first half)
    float* clog_s = (float*)((int*)sd + Emax);           // cross: E_X floats (second half)
    int*   rowptr = (int*)sd + 2 * (size_t)Emax;         // Nmax+1
    int*   count  = rowptr + (size_t)Nmax + 1;           // Nmax
    int*   cursor = count + (size_t)Nmax;                // Nmax
    float* csc    = (float*)(cursor + (size_t)Nmax);     // 2

    const float NEG = -3.4e38f;

    // ---------------- L encoder ----------------
    embed2_kernel<<<cdiv(N_L, 16), 192, 0, stream>>>(x_L, Wemb_L, bemb_L, s_L, N_L, D_L);
    lin2_kernel<<<cdiv(N_L, 16), 192, 0, stream>>>(s_L, Wl_L, bl_L, Wr_L, br_L, xl, xr, N_L);
    fill_i<<<cdiv(N_L, 256), 256, 0, stream>>>(count, 0, N_L);
    hist_kernel<<<cdiv(E_L, 256), 256, 0, stream>>>(edge_L + E_L, count, E_L);
    scan_kernel<<<1, 1024, 0, stream>>>(count, rowptr, cursor, N_L);
    gat_pre_kernel<<<cdiv(E_L, 256), 256, 0, stream>>>(edge_L, edge_L + E_L, pos_L, cursor, sd, E_L);
    gat_fused_kernel<<<cdiv(N_L, 4), 256, 0, stream>>>(rowptr, sd, xl, xr, We_L, att_L, bias_L, s_L, N_L);

    // ---------------- P encoder ----------------
    embed2_kernel<<<cdiv(N_P, 16), 192, 0, stream>>>(x_P, Wemb_P, bemb_P, s_P, N_P, D_P);
    lin2_kernel<<<cdiv(N_P, 16), 192, 0, stream>>>(s_P, Wl_P, bl_P, Wr_P, br_P, xl, xr, N_P);
    fill_i<<<cdiv(N_P, 256), 256, 0, stream>>>(count, 0, N_P);
    hist_kernel<<<cdiv(E_P, 256), 256, 0, stream>>>(edge_P + E_P, count, E_P);
    scan_kernel<<<1, 1024, 0, stream>>>(count, rowptr, cursor, N_P);
    gat_pre_kernel<<<cdiv(E_P, 256), 256, 0, stream>>>(edge_P, edge_P + E_P, pos_P, cursor, sd, E_P);
    gat_fused_kernel<<<cdiv(N_P, 4), 256, 0, stream>>>(rowptr, sd, xl, xr, We_P, att_P, bias_P, s_P, N_P);

    // ---------------- SSM block (L) ----------------
    ssm2_kernel<<<cdiv(N_L, 4), 192, 0, stream>>>(s_L, Win, b_in, Wout, bout, N_L);

    // ---------------- cross attention ----------------
    lin2_kernel<<<cdiv(N_L, 16), 192, 0, stream>>>(s_L, Wq, bq, nullptr, nullptr, xl, nullptr, N_L);
    lin2_kernel<<<cdiv(N_P, 16), 192, 0, stream>>>(s_P, Wk, bk, Wv, bv, xr, vn, N_P);
    fill_i<<<cdiv(N_L, 256), 256, 0, stream>>>(count, 0, N_L);
    hist_kernel<<<cdiv(E_X, 256), 256, 0, stream>>>(ctgt, count, E_X);
    scan_kernel<<<1, 1024, 0, stream>>>(count, rowptr, cursor, N_L);
    cross_pre_kernel<<<cdiv(E_X, 256), 256, 0, stream>>>(csrc, ctgt, cursor, csrc_s, E_X);
    fill_f<<<1, 64, 0, stream>>>(csc, NEG, 1);
    fill_f<<<1, 64, 0, stream>>>(csc + 1, 0.f, 1);
    cross_logit_node_kernel<<<cdiv(N_L, 4), 256, 0, stream>>>(rowptr, csrc_s, xl, xr, clog_s, csc, N_L);
    cross_denom_kernel<<<cdiv(E_X, 256), 256, 0, stream>>>(clog_s, csc, E_X);
    cross_apply_node_kernel<<<cdiv(N_L, 4), 256, 0, stream>>>(rowptr, csrc_s, clog_s, vn, csc, s_L, N_L);

    // ---------------- head ----------------
    head2_kernel<<<cdiv(N_L, 16), 192, 0, stream>>>(s_L, W1, b1, W2, b2, (float*)d_out, N_L);
}